// Round 9
// baseline (132.190 us; speedup 1.0000x reference)
//
#include <hip/hip_runtime.h>
#include <hip/hip_bf16.h>

// QuIP#-style quantized linear. R19 = R18 with host-pass compile fix.
// R18 never ran: __has_builtin(global_load_lds) is FALSE on hipcc's host
// pass -> host compiled the fallback branch, which had a non-constant aux
// for raw_buffer_load_b128. Fix: constant-aux branches in the fallback.
// Experiment (unchanged): split gathers across BOTH return datapaths --
// sgi0 via buffer_load (VGPR return), sgi1 via global_load_lds (per-lane
// global addr, direct LDS deposit, no VGPR writeback) into per-wave 4x1KB
// ring slots, consumed via ds_read_b128 after counted s_waitcnt vmcnt(9)
// + sched_barrier (rule 18). Every iteration issues exactly 3 vmem ops
// (idx, buf-gather, GLDS; dummies in tail) so vmcnt(9) exactly drains the
// slot being read. If the LDS-DMA line pool is disjoint from the VGPR pool:
// qgemm ~35us. If shared: 9th structural null -> ceiling claim.
// prep/zsum = R17 verbatim (3 dispatches, atomic ks-sum).

typedef __attribute__((ext_vector_type(16))) float f32x16;
typedef __attribute__((ext_vector_type(8))) __bf16 bf16x8;
typedef __attribute__((ext_vector_type(4))) __bf16 bf16x4;
typedef __attribute__((ext_vector_type(4))) int i32x4;

#define IN_F 8192
#define OUT_F 8192
#define TOKENS 32
#define KSPLIT 8
#define KCHUNK 1024
#define CH (KCHUNK / 8)            // 128 16B-chunks per token row in LDS
#define GROUPS (KCHUNK / 32)       // 32 pipeline groups (4 codes each)
#define DG 3                       // gather lookahead (groups)
#define DI 5                       // idx lookahead (groups)
#define INV_SQRT_8192 0.011048543456039806f
#define PAD(i) ((i) + ((i) >> 5))

#if __has_builtin(__builtin_amdgcn_raw_buffer_load_b128) && \
    __has_builtin(__builtin_amdgcn_make_buffer_rsrc)
#define HAVE_BUF 1
#else
#define HAVE_BUF 0
#endif

#if __has_builtin(__builtin_amdgcn_global_load_lds)
#define HAVE_GLDS 1
#else
#define HAVE_GLDS 0
#endif

#define KEEP(x) asm volatile("" :: "v"(x))

// ---- H4 butterfly over v[0..3] (2 bits) ----
__device__ inline void h4_reg(float v[4]) {
    float t0 = v[0] + v[1], t1 = v[0] - v[1];
    float t2 = v[2] + v[3], t3 = v[2] - v[3];
    v[0] = t0 + t2; v[1] = t1 + t3; v[2] = t0 - t2; v[3] = t1 - t3;
}

// ---- FWHT-1024, 256 threads. entry: v[j] = elem 4*tid+j.
// exit: v[j] = elem tid + j*256. 1 barrier total.
__device__ inline void fwht1024(float v[4], float* st, int tid) {
    h4_reg(v);                                   // bits 0-1 (j)
    const int lane = tid & 63;
    #pragma unroll
    for (int m = 1; m < 64; m <<= 1) {           // bits 2-7 (lane bits)
        #pragma unroll
        for (int j = 0; j < 4; ++j) {
            float p = __shfl_xor(v[j], m, 64);
            v[j] = (lane & m) ? (p - v[j]) : (v[j] + p);
        }
    }
    #pragma unroll
    for (int j = 0; j < 4; ++j) st[PAD(4 * tid + j)] = v[j];
    __syncthreads();                             // bits 8-9 via LDS exchange
    #pragma unroll
    for (int j = 0; j < 4; ++j) v[j] = st[PAD(tid + j * 256)];
    h4_reg(v);                                   // bits 8-9
}

// ---- kernel 1: cvt + zero z (blocks<512) | fused H8+H1024 input FWHT ----
__global__ __launch_bounds__(256)
void prep_kernel(const float* __restrict__ cb, __bf16* __restrict__ cbb,
                 const float* __restrict__ x, const float* __restrict__ su,
                 __bf16* __restrict__ xh, float* __restrict__ z) {
    __shared__ float st[1056];
    const int tid = threadIdx.x;
    if (blockIdx.x < 512) {
        int i = blockIdx.x * 256 + tid;
        float4 vv = ((const float4*)cb)[i];
        bf16x4 o;
        o[0] = (__bf16)vv.x; o[1] = (__bf16)vv.y;
        o[2] = (__bf16)vv.z; o[3] = (__bf16)vv.w;
        ((bf16x4*)cbb)[i] = o;
        ((float2*)z)[i] = make_float2(0.f, 0.f);   // zero 1MB accumulator
        return;
    }
    const int id = blockIdx.x - 512;                 // 256 fwht tasks
    const int t = id >> 3, ch = id & 7;
    float sgn[8];
    #pragma unroll
    for (int k = 0; k < 8; ++k)
        sgn[k] = (__builtin_popcount(ch & k) & 1) ? -1.f : 1.f;
    float v[4] = {0.f, 0.f, 0.f, 0.f};
    #pragma unroll
    for (int k = 0; k < 8; ++k) {
        float4 xv = *(const float4*)(x + (size_t)t * IN_F + k * 1024 + tid * 4);
        float4 s4 = *(const float4*)(su + k * 1024 + tid * 4);
        v[0] += sgn[k] * xv.x * s4.x;
        v[1] += sgn[k] * xv.y * s4.y;
        v[2] += sgn[k] * xv.z * s4.z;
        v[3] += sgn[k] * xv.w * s4.w;
    }
    fwht1024(v, st, tid);
    __bf16* dst = xh + (size_t)t * IN_F + ch * 1024;
    #pragma unroll
    for (int j = 0; j < 4; ++j)
        dst[tid + j * 256] = (__bf16)(v[j] * INV_SQRT_8192);
}

// ---- kernel 2: z += xh @ W^T (dual-datapath gathers, atomic epilogue) ----
__global__ __launch_bounds__(512, 2)
void qgemm_kernel(const int* __restrict__ qidxs,
                  const __bf16* __restrict__ cb,
                  const __bf16* __restrict__ xh,
                  float* __restrict__ z) {
    __shared__ __align__(16) __bf16 xt[TOKENS * KCHUNK];   // 64 KB
    __shared__ __align__(16) char qs[8 * 4 * 1024];        // 32 KB ring slots
    const int ks = blockIdx.x & (KSPLIT - 1);
    const int nb = blockIdx.x >> 3;
    const int tid = threadIdx.x;
    const int wave = tid >> 6, lane = tid & 63;
    const int h = lane >> 5, lc = lane & 31;
    const int n = nb * 256 + wave * 32 + lc;
    char* qsw = qs + wave * 4096;     // per-wave 4 x 1KB slots

    // stage xh k-slice (32 tok x 1024 k) -> LDS, 16B chunks xor-swizzled
    #pragma unroll
    for (int i = 0; i < 8; ++i) {
        int f = i * 512 + tid, r = f >> 7, c = f & 127;
        i32x4 v = *(const i32x4*)(xh + (size_t)r * IN_F + ks * KCHUNK + c * 8);
        *(i32x4*)(xt + ((r * CH + (c ^ (r & 7))) << 3)) = v;
    }
    __syncthreads();    // the only barrier

    const int* qrow = qidxs + (size_t)n * (IN_F / 8) + ks * (KCHUNK / 8);

#if HAVE_BUF
    // SRD over the bf16 codebook (1 MB). aux=1 -> SC0: L1-bypass, L2-cached.
    __amdgpu_buffer_rsrc_t rsrc = __builtin_amdgcn_make_buffer_rsrc(
        (void*)cb, (short)0, 65536 * 16, 0x00020000);
    #define GA(ix, au) __builtin_bit_cast(bf16x8, \
        __builtin_amdgcn_raw_buffer_load_b128(rsrc, (ix) << 4, 0, au))
#else
    const bf16x8* cbv = (const bf16x8*)cb;
    #define GA(ix, au) (cbv[ix])
#endif

#if HAVE_GLDS
    // per-lane global addr -> LDS deposit at slot + lane*16 (no VGPR return)
    #define GLDS(gp, lp) __builtin_amdgcn_global_load_lds( \
        (const __attribute__((address_space(1))) unsigned int*)(gp), \
        (__attribute__((address_space(3))) unsigned int*)(lp), 16, 0, 0)
#endif

    f32x16 acc;
    #pragma unroll
    for (int i = 0; i < 16; ++i) acc[i] = 0.f;

    i32x4 iv[GROUPS];
    bf16x8 bfr0[GROUPS];
#if !HAVE_GLDS
    bf16x8 bfr1[GROUPS];
#endif

    // uniform pipeline: g = -DI .. GROUPS-1.
    // phase A: iv[g+DI] idx load   (dummy when g+DI >= GROUPS)
    // phase B: buffer gather sgi0 for group g+DG (dummy when >= GROUPS)
    // phase C: global_load_lds gather sgi1 -> slot[(g+DG)&3]   (dummy ditto)
    // consume (g>=0): s_waitcnt vmcnt(9); ds_read slot[g&3]; 2 MFMAs.
    // Dummies keep the younger-op count == 9 for every consume.
    #pragma unroll
    for (int g = -DI; g < GROUPS; ++g) {
        // A
        if (g + DI < GROUPS) {
            iv[g + DI] = *(const i32x4*)(qrow + (g + DI) * 4);
        } else {
            i32x4 d = *(const i32x4*)qrow;
            KEEP(d[0]);
        }
        // B + C
        if (g + DG >= 0) {
            const int gg = g + DG;
            if (gg < GROUPS) {
                if (gg & 1) bfr0[gg] = GA(h ? iv[gg][1] : iv[gg][0], 1);
                else        bfr0[gg] = GA(h ? iv[gg][1] : iv[gg][0], 0);
                const unsigned ci = (unsigned)(h ? iv[gg][3] : iv[gg][2]);
#if HAVE_GLDS
                GLDS((const char*)cb + ((size_t)ci << 4),
                     qsw + (gg & 3) * 1024);
#else
                if (gg & 1) bfr1[gg] = GA((int)ci, 1);
                else        bfr1[gg] = GA((int)ci, 0);
#endif
            } else {
                bf16x8 d2 = GA(0, 0);
                KEEP(__builtin_bit_cast(i32x4, d2)[0]);
#if HAVE_GLDS
                GLDS((const char*)cb, qsw + (gg & 3) * 1024);
#endif
            }
        }
        // consume
        if (g >= 0) {
#if HAVE_GLDS
            asm volatile("s_waitcnt vmcnt(9)" ::: "memory");
            __builtin_amdgcn_sched_barrier(0);
            bf16x8 b1 = *(const bf16x8*)(qsw + (g & 3) * 1024 + lane * 16);
#else
            bf16x8 b1 = bfr1[g];
#endif
            const int T0 = 2 * g, T1 = 2 * g + 1;
            bf16x8 a0 = *(const bf16x8*)(xt +
                          ((lc * CH + ((2 * T0 + h) ^ (lc & 7))) << 3));
            acc = __builtin_amdgcn_mfma_f32_32x32x16_bf16(a0, bfr0[g],
                                                          acc, 0, 0, 0);
            bf16x8 a1 = *(const bf16x8*)(xt +
                          ((lc * CH + ((2 * T1 + h) ^ (lc & 7))) << 3));
            acc = __builtin_amdgcn_mfma_f32_32x32x16_bf16(a1, b1,
                                                          acc, 0, 0, 0);
        }
    }

    // D[m=(r&3)+4h+8(r>>2)][n=lc] -> fp32 atomic ks-sum into z[t][n]
    #pragma unroll
    for (int r = 0; r < 16; ++r) {
        int m = (r & 3) + 4 * h + 8 * (r >> 2);
        atomicAdd(z + (size_t)m * OUT_F + n, acc[r]);
    }
}

// ---- kernel 3: out = H1024( H8-first(z) ) * scale * sv ------------------
__global__ __launch_bounds__(256)
void zsum_kernel(const float* __restrict__ z, const float* __restrict__ sv,
                 const float* __restrict__ wscale, float* __restrict__ out) {
    __shared__ float st[1056];
    const int tid = threadIdx.x;
    const int t = blockIdx.x >> 3, ch = blockIdx.x & 7;  // 256 blocks
    float sgn[8];
    #pragma unroll
    for (int k = 0; k < 8; ++k)
        sgn[k] = (__builtin_popcount(ch & k) & 1) ? -1.f : 1.f;
    float v[4] = {0.f, 0.f, 0.f, 0.f};
    #pragma unroll
    for (int kk = 0; kk < 8; ++kk) {
        float4 zv = *(const float4*)(z + (size_t)t * OUT_F + kk * 1024 + tid * 4);
        v[0] += sgn[kk] * zv.x;
        v[1] += sgn[kk] * zv.y;
        v[2] += sgn[kk] * zv.z;
        v[3] += sgn[kk] * zv.w;
    }
    fwht1024(v, st, tid);
    const float sc = INV_SQRT_8192 * wscale[0];
    float* dst = out + (size_t)t * OUT_F + ch * 1024;
    const float* svp = sv + ch * 1024;
    #pragma unroll
    for (int j = 0; j < 4; ++j)
        dst[tid + j * 256] = v[j] * sc * svp[tid + j * 256];
}

extern "C" void kernel_launch(void* const* d_in, const int* in_sizes, int n_in,
                              void* d_out, int out_size, void* d_ws, size_t ws_size,
                              hipStream_t stream) {
    const float* x      = (const float*)d_in[0];   // (32, 8192)
    const float* cb     = (const float*)d_in[1];   // (65536, 8)
    const int*   qidxs  = (const int*)d_in[2];     // (8192, 1024)
    const float* su     = (const float*)d_in[3];   // (8192,)
    const float* sv     = (const float*)d_in[4];   // (8192,)
    const float* wscale = (const float*)d_in[5];   // scalar
    float* out = (float*)d_out;                    // (32, 8192) fp32

    char* ws = (char*)d_ws;
    __bf16* cbb = (__bf16*)ws;                                // 1 MB
    __bf16* xh  = (__bf16*)(ws + (1u << 20));                 // 512 KB
    float*  z   = (float*)(ws + (1u << 20) + (512u << 10));   // 1 MB fp32

    hipLaunchKernelGGL(prep_kernel, dim3(768), dim3(256), 0, stream,
                       cb, cbb, x, su, xh, z);
    hipLaunchKernelGGL(qgemm_kernel, dim3(32 * KSPLIT), dim3(512), 0, stream,
                       qidxs, cbb, xh, z);
    hipLaunchKernelGGL(zsum_kernel, dim3(256), dim3(256), 0, stream,
                       z, sv, wscale, out);
}

// Round 10
// 131.468 us; speedup vs baseline: 1.0055x; 1.0055x over previous
//
#include <hip/hip_runtime.h>
#include <hip/hip_bf16.h>

// QuIP#-style quantized linear. R20: route 6.25% of gathers to the LDS pipe.
// Ledger: fill(46.5, harness) + qgemm(gather wall) + ~35us fixed.
// Gather wall = per-CU outstanding-line pool (~64 x ~220cy => ~3cy/lane-req,
// 32768 req/CU = 46us). NINE nulls: L1/sc0/mixed paths, occupancy x2.2,
// depth x4, KSPLIT, idx-coalescing, idx-restage, R19's global_load_lds
// deposit (SHARES the pool: 52us, reverted).
// R20 (last untested datapath): stage codebook entries [0,4096) (64KB bf16)
// in LDS next to xt (128KB static, 1 blk/CU, 8 waves x ~10 in-flight = 80
// > 64 still saturates). Per-lane predicate ci<4096 -> ds_read_b128 (LGKM
// pipe, concurrent with VMEM); those lanes are exec-masked OFF the
// buffer_load => their VMEM requests are genuinely removed (-6.25%).
// Base = R17 champion (127.70us): 3 dispatches, atomic ks-sum epilogue,
// gather pipeline byte-identical except the per-lane source select.

typedef __attribute__((ext_vector_type(16))) float f32x16;
typedef __attribute__((ext_vector_type(8))) __bf16 bf16x8;
typedef __attribute__((ext_vector_type(4))) __bf16 bf16x4;
typedef __attribute__((ext_vector_type(4))) int i32x4;

#define IN_F 8192
#define OUT_F 8192
#define TOKENS 32
#define KSPLIT 8
#define KCHUNK 1024
#define CH (KCHUNK / 8)            // 128 16B-chunks per token row in LDS
#define GROUPS (KCHUNK / 32)       // 32 pipeline groups (4 codes each)
#define DG 5                       // gather lookahead (groups)
#define DI 7                       // idx lookahead (groups)
#define LSLICE 4096u               // codebook entries resident in LDS (64KB)
#define INV_SQRT_8192 0.011048543456039806f
#define PAD(i) ((i) + ((i) >> 5))

#if __has_builtin(__builtin_amdgcn_raw_buffer_load_b128) && \
    __has_builtin(__builtin_amdgcn_make_buffer_rsrc)
#define HAVE_BUF 1
#else
#define HAVE_BUF 0
#endif

// ---- H4 butterfly over v[0..3] (2 bits) ----
__device__ inline void h4_reg(float v[4]) {
    float t0 = v[0] + v[1], t1 = v[0] - v[1];
    float t2 = v[2] + v[3], t3 = v[2] - v[3];
    v[0] = t0 + t2; v[1] = t1 + t3; v[2] = t0 - t2; v[3] = t1 - t3;
}

// ---- FWHT-1024, 256 threads. entry: v[j] = elem 4*tid+j.
// exit: v[j] = elem tid + j*256. 1 barrier total.
__device__ inline void fwht1024(float v[4], float* st, int tid) {
    h4_reg(v);                                   // bits 0-1 (j)
    const int lane = tid & 63;
    #pragma unroll
    for (int m = 1; m < 64; m <<= 1) {           // bits 2-7 (lane bits)
        #pragma unroll
        for (int j = 0; j < 4; ++j) {
            float p = __shfl_xor(v[j], m, 64);
            v[j] = (lane & m) ? (p - v[j]) : (v[j] + p);
        }
    }
    #pragma unroll
    for (int j = 0; j < 4; ++j) st[PAD(4 * tid + j)] = v[j];
    __syncthreads();                             // bits 8-9 via LDS exchange
    #pragma unroll
    for (int j = 0; j < 4; ++j) v[j] = st[PAD(tid + j * 256)];
    h4_reg(v);                                   // bits 8-9
}

// ---- kernel 1: cvt + zero z (blocks<512) | fused H8+H1024 input FWHT ----
__global__ __launch_bounds__(256)
void prep_kernel(const float* __restrict__ cb, __bf16* __restrict__ cbb,
                 const float* __restrict__ x, const float* __restrict__ su,
                 __bf16* __restrict__ xh, float* __restrict__ z) {
    __shared__ float st[1056];
    const int tid = threadIdx.x;
    if (blockIdx.x < 512) {
        int i = blockIdx.x * 256 + tid;
        float4 vv = ((const float4*)cb)[i];
        bf16x4 o;
        o[0] = (__bf16)vv.x; o[1] = (__bf16)vv.y;
        o[2] = (__bf16)vv.z; o[3] = (__bf16)vv.w;
        ((bf16x4*)cbb)[i] = o;
        ((float2*)z)[i] = make_float2(0.f, 0.f);   // zero 1MB accumulator
        return;
    }
    const int id = blockIdx.x - 512;                 // 256 fwht tasks
    const int t = id >> 3, ch = id & 7;
    float sgn[8];
    #pragma unroll
    for (int k = 0; k < 8; ++k)
        sgn[k] = (__builtin_popcount(ch & k) & 1) ? -1.f : 1.f;
    float v[4] = {0.f, 0.f, 0.f, 0.f};
    #pragma unroll
    for (int k = 0; k < 8; ++k) {
        float4 xv = *(const float4*)(x + (size_t)t * IN_F + k * 1024 + tid * 4);
        float4 s4 = *(const float4*)(su + k * 1024 + tid * 4);
        v[0] += sgn[k] * xv.x * s4.x;
        v[1] += sgn[k] * xv.y * s4.y;
        v[2] += sgn[k] * xv.z * s4.z;
        v[3] += sgn[k] * xv.w * s4.w;
    }
    fwht1024(v, st, tid);
    __bf16* dst = xh + (size_t)t * IN_F + ch * 1024;
    #pragma unroll
    for (int j = 0; j < 4; ++j)
        dst[tid + j * 256] = (__bf16)(v[j] * INV_SQRT_8192);
}

// ---- kernel 2: z += xh @ W^T (LDS-slice + buffer gathers, atomic epi) ----
__global__ __launch_bounds__(512, 2)
void qgemm_kernel(const int* __restrict__ qidxs,
                  const __bf16* __restrict__ cb,
                  const __bf16* __restrict__ xh,
                  float* __restrict__ z) {
    __shared__ __align__(16) __bf16 xt[TOKENS * KCHUNK];   // 64 KB
    __shared__ __align__(16) __bf16 cbl[LSLICE * 8];       // 64 KB cb slice
    const int ks = blockIdx.x & (KSPLIT - 1);
    const int nb = blockIdx.x >> 3;
    const int tid = threadIdx.x;
    const int wave = tid >> 6, lane = tid & 63;
    const int h = lane >> 5, lc = lane & 31;
    const int n = nb * 256 + wave * 32 + lc;

    // stage xh k-slice (32 tok x 1024 k) -> LDS, 16B chunks xor-swizzled
    #pragma unroll
    for (int i = 0; i < 8; ++i) {
        int f = i * 512 + tid, r = f >> 7, c = f & 127;
        i32x4 v = *(const i32x4*)(xh + (size_t)r * IN_F + ks * KCHUNK + c * 8);
        *(i32x4*)(xt + ((r * CH + (c ^ (r & 7))) << 3)) = v;
    }
    // stage codebook slice [0, LSLICE) -> LDS, coalesced 16B/lane
    #pragma unroll
    for (int i = 0; i < 8; ++i) {
        int e = i * 512 + tid;
        *(i32x4*)(cbl + (size_t)e * 8) = *(const i32x4*)(cb + (size_t)e * 8);
    }
    __syncthreads();    // the only barrier

    const int* qrow = qidxs + (size_t)n * (IN_F / 8) + ks * (KCHUNK / 8);

#if HAVE_BUF
    // SRD over the bf16 codebook (1 MB). aux=1 -> SC0: L1-bypass, L2-cached.
    __amdgpu_buffer_rsrc_t rsrc = __builtin_amdgcn_make_buffer_rsrc(
        (void*)cb, (short)0, 65536 * 16, 0x00020000);
    #define GA(ix, au) __builtin_bit_cast(bf16x8, \
        __builtin_amdgcn_raw_buffer_load_b128(rsrc, (int)(ix) << 4, 0, au))
#else
    const bf16x8* cbv = (const bf16x8*)cb;
    #define GA(ix, au) (cbv[ix])
#endif

    // per-lane source select: LDS slice (LGKM pipe) or buffer_load (VMEM).
    // Lanes taking the LDS path are exec-masked off the buffer_load ->
    // their VMEM line-requests are removed from the walled pool.
    #define GSEL(dst, ix, au) do { unsigned _ix = (unsigned)(ix);           \
        if (_ix < LSLICE) dst = *(const bf16x8*)(cbl + (size_t)_ix * 8);    \
        else              dst = GA(_ix, au); } while (0)

    f32x16 acc;
    #pragma unroll
    for (int i = 0; i < 16; ++i) acc[i] = 0.f;

    i32x4 iv[GROUPS];
    bf16x8 bfr[GROUPS][2];

    #pragma unroll
    for (int g = 0; g < DI; ++g)
        iv[g] = *(const i32x4*)(qrow + g * 4);
    #pragma unroll
    for (int g = 0; g < DG; ++g) {
        if (g & 1) {
            GSEL(bfr[g][0], h ? iv[g][1] : iv[g][0], 1);
            GSEL(bfr[g][1], h ? iv[g][3] : iv[g][2], 1);
        } else {
            GSEL(bfr[g][0], h ? iv[g][1] : iv[g][0], 0);
            GSEL(bfr[g][1], h ? iv[g][3] : iv[g][2], 0);
        }
    }

    #pragma unroll
    for (int g = 0; g < GROUPS; ++g) {
        if (g + DI < GROUPS)
            iv[g + DI] = *(const i32x4*)(qrow + (g + DI) * 4);
        if (g + DG < GROUPS) {
            if ((g + DG) & 1) {
                GSEL(bfr[g + DG][0], h ? iv[g + DG][1] : iv[g + DG][0], 1);
                GSEL(bfr[g + DG][1], h ? iv[g + DG][3] : iv[g + DG][2], 1);
            } else {
                GSEL(bfr[g + DG][0], h ? iv[g + DG][1] : iv[g + DG][0], 0);
                GSEL(bfr[g + DG][1], h ? iv[g + DG][3] : iv[g + DG][2], 0);
            }
        }
        #pragma unroll
        for (int sgi = 0; sgi < 2; ++sgi) {
            const int T = 2 * g + sgi;
            bf16x8 a = *(const bf16x8*)(xt +
                          ((lc * CH + ((2 * T + h) ^ (lc & 7))) << 3));
            acc = __builtin_amdgcn_mfma_f32_32x32x16_bf16(a, bfr[g][sgi],
                                                          acc, 0, 0, 0);
        }
    }

    // D[m=(r&3)+4h+8(r>>2)][n=lc] -> fp32 atomic ks-sum into z[t][n]
    #pragma unroll
    for (int r = 0; r < 16; ++r) {
        int m = (r & 3) + 4 * h + 8 * (r >> 2);
        atomicAdd(z + (size_t)m * OUT_F + n, acc[r]);
    }
}

// ---- kernel 3: out = H1024( H8-first(z) ) * scale * sv ------------------
__global__ __launch_bounds__(256)
void zsum_kernel(const float* __restrict__ z, const float* __restrict__ sv,
                 const float* __restrict__ wscale, float* __restrict__ out) {
    __shared__ float st[1056];
    const int tid = threadIdx.x;
    const int t = blockIdx.x >> 3, ch = blockIdx.x & 7;  // 256 blocks
    float sgn[8];
    #pragma unroll
    for (int k = 0; k < 8; ++k)
        sgn[k] = (__builtin_popcount(ch & k) & 1) ? -1.f : 1.f;
    float v[4] = {0.f, 0.f, 0.f, 0.f};
    #pragma unroll
    for (int kk = 0; kk < 8; ++kk) {
        float4 zv = *(const float4*)(z + (size_t)t * OUT_F + kk * 1024 + tid * 4);
        v[0] += sgn[kk] * zv.x;
        v[1] += sgn[kk] * zv.y;
        v[2] += sgn[kk] * zv.z;
        v[3] += sgn[kk] * zv.w;
    }
    fwht1024(v, st, tid);
    const float sc = INV_SQRT_8192 * wscale[0];
    float* dst = out + (size_t)t * OUT_F + ch * 1024;
    const float* svp = sv + ch * 1024;
    #pragma unroll
    for (int j = 0; j < 4; ++j)
        dst[tid + j * 256] = v[j] * sc * svp[tid + j * 256];
}

extern "C" void kernel_launch(void* const* d_in, const int* in_sizes, int n_in,
                              void* d_out, int out_size, void* d_ws, size_t ws_size,
                              hipStream_t stream) {
    const float* x      = (const float*)d_in[0];   // (32, 8192)
    const float* cb     = (const float*)d_in[1];   // (65536, 8)
    const int*   qidxs  = (const int*)d_in[2];     // (8192, 1024)
    const float* su     = (const float*)d_in[3];   // (8192,)
    const float* sv     = (const float*)d_in[4];   // (8192,)
    const float* wscale = (const float*)d_in[5];   // scalar
    float* out = (float*)d_out;                    // (32, 8192) fp32

    char* ws = (char*)d_ws;
    __bf16* cbb = (__bf16*)ws;                                // 1 MB
    __bf16* xh  = (__bf16*)(ws + (1u << 20));                 // 512 KB
    float*  z   = (float*)(ws + (1u << 20) + (512u << 10));   // 1 MB fp32

    hipLaunchKernelGGL(prep_kernel, dim3(768), dim3(256), 0, stream,
                       cb, cbb, x, su, xh, z);
    hipLaunchKernelGGL(qgemm_kernel, dim3(32 * KSPLIT), dim3(512), 0, stream,
                       qidxs, cbb, xh, z);
    hipLaunchKernelGGL(zsum_kernel, dim3(256), dim3(256), 0, stream,
                       z, sv, wscale, out);
}